// Round 17
// baseline (242.368 us; speedup 1.0000x reference)
//
#include <hip/hip_runtime.h>
#include <stdint.h>

// ---------- types / helpers ----------
typedef __attribute__((ext_vector_type(8))) short short8;
typedef __attribute__((ext_vector_type(4))) float f32x4;
typedef __attribute__((ext_vector_type(4))) int   i32x4;

#define GLDS16(gp, lp)                                              \
  __builtin_amdgcn_global_load_lds(                                  \
      (const __attribute__((address_space(1))) void*)(gp),           \
      (__attribute__((address_space(3))) void*)(lp), 16, 0, 0)

// ---------- kernel 1: per-row i8 quantization of h ----------
__global__ void __launch_bounds__(256) quant_h_kernel(const float* __restrict__ h,
                                                      signed char* __restrict__ hQ,
                                                      float* __restrict__ sRow,
                                                      int M) {
  const int row  = blockIdx.x * 4 + (threadIdx.x >> 6);
  const int lane = threadIdx.x & 63;
  if (row >= M) return;
  const float4 v0 = *(const float4*)(h + (size_t)row * 512 + lane * 8);
  const float4 v1 = *(const float4*)(h + (size_t)row * 512 + lane * 8 + 4);
  float mx = fmaxf(fmaxf(fmaxf(fabsf(v0.x), fabsf(v0.y)), fmaxf(fabsf(v0.z), fabsf(v0.w))),
                   fmaxf(fmaxf(fabsf(v1.x), fabsf(v1.y)), fmaxf(fabsf(v1.z), fabsf(v1.w))));
#pragma unroll
  for (int o = 32; o > 0; o >>= 1) mx = fmaxf(mx, __shfl_xor(mx, o));
  mx = fmaxf(mx, 1e-20f);
  const float inv = 127.0f / mx;
  int q0 = __float2int_rn(v0.x * inv), q1 = __float2int_rn(v0.y * inv);
  int q2 = __float2int_rn(v0.z * inv), q3 = __float2int_rn(v0.w * inv);
  int q4 = __float2int_rn(v1.x * inv), q5 = __float2int_rn(v1.y * inv);
  int q6 = __float2int_rn(v1.z * inv), q7 = __float2int_rn(v1.w * inv);
  const unsigned lo = (q0 & 255) | ((q1 & 255) << 8) | ((q2 & 255) << 16) | ((q3 & 255) << 24);
  const unsigned hi = (q4 & 255) | ((q5 & 255) << 8) | ((q6 & 255) << 16) | ((q7 & 255) << 24);
  *(uint2*)(hQ + (size_t)row * 512 + lane * 8) = make_uint2(lo, hi);
  if (lane == 0) sRow[row] = mx * (1.0f / 127.0f);
}

// ---------- kernel 2: BTq[n][k] = i8(W1[(n>=512?512:0)+k][n&511] / SB) ----------
__global__ void __launch_bounds__(256) buildBTq_kernel(const float* __restrict__ W1,
                                                       signed char* __restrict__ BTq) {
  int t = blockIdx.x * 256 + threadIdx.x;   // 0..524287
  int n = t >> 9;
  int k = t & 511;
  float v = W1[((size_t)((n >> 9) * 512 + k)) * 512 + (size_t)(n & 511)];
  int q = __float2int_rn(v * (127.0f / 0.03125f));
  q = q > 127 ? 127 : (q < -127 ? -127 : q);
  BTq[t] = (signed char)q;
}

// ---------- kernel 3: FUSED edge GEMM — FRAGMENT-LINEAR LDS (conflict-free) ----------
// R16 structure (sync/loops identical), but LDS stores A and B in fragment
// order: chunk (tile,kt) of 1024B = one wave fragment; lane l holds
// (row = tile*16 + (l&15), k = kt*64 + (l>>4)*16). All ds_reads are
// base + lane*16 (linear, 0 conflicts); glds dest stays linear; the
// fragment gather moves to the per-lane GLOBAL address.
__global__ void __launch_bounds__(256) edge_gemm_kernel(
    const signed char* __restrict__ hQ, const signed char* __restrict__ BTq,
    const float* __restrict__ sRow, const float* __restrict__ b1,
    const float* __restrict__ W2, const float* __restrict__ b2,
    const int* __restrict__ src, const int* __restrict__ dst,
    float* __restrict__ out, int E) {
  __shared__ signed char S[64 * 1024];   // 64 KB: A1|A2 in prologue, Ba|Bb per jt

  const int e0   = blockIdx.x * 64;
  const int tid  = threadIdx.x;
  const int lane = tid & 63;
  const int wid  = tid >> 6;
  const int wr   = wid >> 1, wc = wid & 1;   // wave: edges [wr*32,+32) x j [wc*32,+32)
  const int lr   = lane & 15;
  const int g    = lane >> 4;                // 0..3

  // per-lane staging constants: chunk c = q*4 + wid; within chunk,
  // row-in-tile = lane&15, k-off = (lane>>4)*16
  const int kin = (lane >> 4) * 16;

  // ---- prologue: gather A1/A2 in fragment order ----
  // chunk c (0..31): rt = c>>3 (16-edge tile), kt = c&7 (64-k tile)
#pragma unroll
  for (int q = 0; q < 8; ++q) {
    const int c   = q * 4 + wid;
    const int rt  = c >> 3;
    const int kt  = c & 7;
    int es = e0 + rt * 16 + lr; es = es < E ? es : E - 1;
    const size_t koff = (size_t)(kt * 64 + kin);
    GLDS16(hQ + (size_t)src[es] * 512 + koff, S + (q * 256 + tid) * 16);
    GLDS16(hQ + (size_t)dst[es] * 512 + koff, S + 32768 + (q * 256 + tid) * 16);
  }

  // per-edge scales (output row r maps to edge e0 + wr*32 + i*16 + g*4 + r)
  const float SB = 0.03125f / 127.0f;
  float s1v[2][4], s2v[2][4];
#pragma unroll
  for (int i = 0; i < 2; ++i)
#pragma unroll
    for (int r = 0; r < 4; ++r) {
      int e = e0 + wr * 32 + i * 16 + g * 4 + r; e = e < E ? e : E - 1;
      s1v[i][r] = sRow[src[e]] * SB;
      s2v[i][r] = sRow[dst[e]] * SB;
    }

  __syncthreads();                           // A staged

  // ---- A -> registers: aF[i][kt] = chunk (wr*2+i, kt), linear read ----
  i32x4 aF1[2][8], aF2[2][8];
#pragma unroll
  for (int i = 0; i < 2; ++i) {
    const int rt = wr * 2 + i;
#pragma unroll
    for (int kt = 0; kt < 8; ++kt) {
      const int off = (rt * 8 + kt) * 1024 + lane * 16;
      aF1[i][kt] = *(const i32x4*)&S[off];
      aF2[i][kt] = *(const i32x4*)&S[32768 + off];
    }
  }
  __syncthreads();                           // all waves hold A in regs; S free

  float sc[2][4];
#pragma unroll
  for (int i = 0; i < 2; ++i)
#pragma unroll
    for (int r = 0; r < 4; ++r) sc[i][r] = 0.f;

  // ---- main: 8 j-tiles of 64 ----
#pragma unroll 1
  for (int jt = 0; jt < 8; ++jt) {
    // stage Ba/Bb in fragment order: chunk c: jj2 = c>>3 (16-j tile), kt = c&7
#pragma unroll
    for (int q = 0; q < 8; ++q) {
      const int c   = q * 4 + wid;
      const int jj2 = c >> 3;
      const int kt  = c & 7;
      const size_t grow = (size_t)(jt * 64 + jj2 * 16 + lr);
      const size_t koff = (size_t)(kt * 64 + kin);
      GLDS16(BTq + grow * 512 + koff, S + (q * 256 + tid) * 16);
      GLDS16(BTq + (grow + 512) * 512 + koff, S + 32768 + (q * 256 + tid) * 16);
    }
    __syncthreads();                         // B tile ready

    i32x4 acc1[2][2], acc2[2][2];
#pragma unroll
    for (int i = 0; i < 2; ++i)
#pragma unroll
      for (int jj = 0; jj < 2; ++jj) { acc1[i][jj] = (i32x4){0,0,0,0}; acc2[i][jj] = (i32x4){0,0,0,0}; }

    // 8 kt steps, no barriers (buffer static within jt); all reads linear
#pragma unroll
    for (int kt = 0; kt < 8; ++kt) {
      i32x4 bF[2], dF[2];
#pragma unroll
      for (int jj = 0; jj < 2; ++jj) {
        const int off = ((wc * 2 + jj) * 8 + kt) * 1024 + lane * 16;
        bF[jj] = *(const i32x4*)&S[off];
        dF[jj] = *(const i32x4*)&S[32768 + off];
      }
#pragma unroll
      for (int i = 0; i < 2; ++i)
#pragma unroll
        for (int jj = 0; jj < 2; ++jj) {
          asm("v_mfma_i32_16x16x64_i8 %0, %1, %2, %0" : "+v"(acc1[i][jj]) : "v"(aF1[i][kt]), "v"(bF[jj]));
          asm("v_mfma_i32_16x16x64_i8 %0, %1, %2, %0" : "+v"(acc2[i][jj]) : "v"(aF2[i][kt]), "v"(dF[jj]));
        }
    }

    // jt epilogue: fold into score
#pragma unroll
    for (int jj = 0; jj < 2; ++jj) {
      const int j = jt * 64 + wc * 32 + jj * 16 + lr;
      const float bb = b1[j];
      const float ww = W2[j];
#pragma unroll
      for (int i = 0; i < 2; ++i)
#pragma unroll
        for (int r = 0; r < 4; ++r) {
          const float hv = s1v[i][r] * (float)acc1[i][jj][r]
                         + s2v[i][r] * (float)acc2[i][jj][r] + bb;
          sc[i][r] += fmaxf(hv, 0.f) * ww;
        }
    }
    __syncthreads();                         // all B reads done -> restage safe
  }

  // ---- reduce: across lr (16 j-lanes), then across wc via LDS ----
#pragma unroll
  for (int i = 0; i < 2; ++i)
#pragma unroll
    for (int r = 0; r < 4; ++r) {
      sc[i][r] += __shfl_xor(sc[i][r], 1);
      sc[i][r] += __shfl_xor(sc[i][r], 2);
      sc[i][r] += __shfl_xor(sc[i][r], 4);
      sc[i][r] += __shfl_xor(sc[i][r], 8);
    }
  float* scW = (float*)S;
  if (lr == 0) {
#pragma unroll
    for (int i = 0; i < 2; ++i)
#pragma unroll
      for (int r = 0; r < 4; ++r)
        scW[wc * 64 + wr * 32 + i * 16 + g * 4 + r] = sc[i][r];
  }
  __syncthreads();
  if (tid < 64 && e0 + tid < E)
    out[e0 + tid] = scW[tid] + scW[64 + tid] + b2[0];
}

// ---------- launcher ----------
extern "C" void kernel_launch(void* const* d_in, const int* in_sizes, int n_in,
                              void* d_out, int out_size, void* d_ws, size_t ws_size,
                              hipStream_t stream) {
  const float* h  = (const float*)d_in[0];
  const int*   src = (const int*)d_in[1];
  const int*   dst = (const int*)d_in[2];
  const float* W1 = (const float*)d_in[3];
  const float* b1 = (const float*)d_in[4];
  const float* W2 = (const float*)d_in[5];
  const float* b2 = (const float*)d_in[6];
  float* out = (float*)d_out;

  const int M = in_sizes[0] / 512;   // 100000 nodes
  const int E = in_sizes[1];         // 160000 edges

  char* ws = (char*)d_ws;
  signed char* hQ = (signed char*)ws;                                  // M*512 i8
  size_t off = (((size_t)M * 512) + 255) & ~(size_t)255;
  float* sRow = (float*)(ws + off);                                    // M f32
  off += (((size_t)M * 4) + 255) & ~(size_t)255;
  signed char* BTq = (signed char*)(ws + off);                         // 1024*512 i8

  quant_h_kernel<<<(M + 3) / 4, 256, 0, stream>>>(h, hQ, sRow, M);
  buildBTq_kernel<<<2048, 256, 0, stream>>>(W1, BTq);
  edge_gemm_kernel<<<(E + 63) / 64, 256, 0, stream>>>(hQ, BTq, sRow, b1, W2, b2,
                                                      src, dst, out, E);
}